// Round 1
// baseline (39.797 us; speedup 1.0000x reference)
//
#include <hip/hip_runtime.h>

#define NN 128
#define CCH 16
#define BBATCH 4
#define GP 4   // p-rows per block in kernel1
#define HID 128

// ---------------------------------------------------------------------------
// Kernel 1: per block (b, c, pgrp): compute rows p = pgrp*GP .. pgrp*GP+GP-1
// of out[b,c]. Thread q handles pairs (p_i, q). Off-diagonal: h1. Diagonal:
// (1/127) * sum_{q != p} h0  (block reduction).
// ---------------------------------------------------------------------------
__global__ __launch_bounds__(128) void k1_mlp(
    const float* __restrict__ x, const float* __restrict__ W1,
    const float* __restrict__ b1, const float* __restrict__ W2,
    const float* __restrict__ b2, float* __restrict__ out)
{
    __shared__ float4 w1s[HID];   // W1 rows (4 floats each)
    __shared__ float4 wbs[HID];   // {b1[k], W2[0][k], W2[1][k], 0}
    __shared__ float partial[2][GP];

    const int t = threadIdx.x;    // q = t
    // stage weights (128 threads, one hidden unit each)
    w1s[t] = reinterpret_cast<const float4*>(W1)[t];
    wbs[t] = make_float4(b1[t], W2[t], W2[HID + t], 0.f);

    const int bid = blockIdx.x;
    const int pg = bid & (NN / GP - 1);
    const int c  = (bid / (NN / GP)) & (CCH - 1);
    const int b  = bid / ((NN / GP) * CCH);
    const int p0 = pg * GP;

    const float* xm = x + (size_t)(b * CCH + c) * NN * NN;
    const int q = t;

    const float x_qq = xm[q * NN + q];
    // column slice x[q][p0..p0+3] in one dwordx4
    const float4 colv = *reinterpret_cast<const float4*>(&xm[q * NN + p0]);
    float x_qp[GP] = { colv.x, colv.y, colv.z, colv.w };
    float x_pq[GP], x_pp[GP];
    #pragma unroll
    for (int i = 0; i < GP; ++i) {
        const int p = p0 + i;
        x_pp[i] = xm[p * NN + p];   // uniform per block -> scalar load
        x_pq[i] = xm[p * NN + q];   // coalesced row load
    }
    const float bb0 = b2[0], bb1 = b2[1];
    float h0[GP], h1[GP];
    #pragma unroll
    for (int i = 0; i < GP; ++i) { h0[i] = bb0; h1[i] = bb1; }

    __syncthreads();

    #pragma unroll 8
    for (int k = 0; k < HID; ++k) {
        const float4 w  = w1s[k];
        const float4 wb = wbs[k];
        #pragma unroll
        for (int i = 0; i < GP; ++i) {
            float hd = fmaf(w.x, x_pp[i], wb.x);
            hd = fmaf(w.y, x_pq[i], hd);
            hd = fmaf(w.z, x_qp[i], hd);
            hd = fmaf(w.w, x_qq, hd);
            hd = fmaxf(hd, 0.f);
            h0[i] = fmaf(wb.y, hd, h0[i]);
            h1[i] = fmaf(wb.z, hd, h1[i]);
        }
    }

    float* orow = out + (size_t)(b * CCH + c) * NN * NN;
    #pragma unroll
    for (int i = 0; i < GP; ++i) {
        const int p = p0 + i;
        if (q != p) orow[p * NN + q] = h1[i];
        if (q == p) h0[i] = 0.f;     // exclude from diagonal sum
    }

    // block-reduce h0[i] over 128 threads (2 waves)
    #pragma unroll
    for (int i = 0; i < GP; ++i) {
        float v = h0[i];
        for (int off = 32; off > 0; off >>= 1)
            v += __shfl_down(v, off, 64);
        if ((t & 63) == 0) partial[t >> 6][i] = v;
    }
    __syncthreads();
    if (t < GP) {
        const int p = p0 + t;
        orow[p * NN + p] = (partial[0][t] + partial[1][t]) * (1.0f / 127.0f);
    }
}

// ---------------------------------------------------------------------------
// Kernel 2: per block (b, nrow): y[b, d, nrow, m] =
//   relu( sum_c out[b,c,nrow,m] * Wc[d][c] + bc[d] ),  d=0..127, m=0..127.
// 256 threads: thread = (dgrp = t>>5) x (mq = t&31, m0 = 4*mq), 16 d's each,
// float4 over m.
// ---------------------------------------------------------------------------
__global__ __launch_bounds__(256) void k2_conv(
    const float* __restrict__ outm, const float* __restrict__ Wc,
    const float* __restrict__ bc, float* __restrict__ y)
{
    __shared__ float s_out[CCH][NN];   // 8 KiB
    __shared__ float wcs[128][CCH];    // 8 KiB
    __shared__ float bcs[128];

    const int t = threadIdx.x;
    const int bid = blockIdx.x;
    const int nrow = bid & (NN - 1);
    const int b = bid / NN;

    // stage Wc (2048 floats, row-major [128][16]) + bc
    #pragma unroll
    for (int i = 0; i < 8; ++i) {
        const int idx = t + i * 256;
        reinterpret_cast<float*>(wcs)[idx] = Wc[idx];
    }
    if (t < 128) bcs[t] = bc[t];

    // stage out[b, 0..15, nrow, :]
    const float* obase = outm + ((size_t)(b * CCH) * NN + nrow) * NN;
    #pragma unroll
    for (int i = 0; i < 8; ++i) {
        const int idx = t + i * 256;
        const int c = idx >> 7, m = idx & 127;
        s_out[c][m] = obase[(size_t)c * NN * NN + m];
    }
    __syncthreads();

    const int m0 = (t & 31) * 4;
    const int dgrp = t >> 5;   // 0..7

    float4 r[CCH];
    #pragma unroll
    for (int c2 = 0; c2 < CCH; ++c2)
        r[c2] = *reinterpret_cast<const float4*>(&s_out[c2][m0]);

    float* ybase = y + ((size_t)b * 128 * NN + nrow) * NN;
    #pragma unroll
    for (int dd = 0; dd < 16; ++dd) {
        const int d = dgrp * 16 + dd;
        const float bcv = bcs[d];
        float4 acc = make_float4(bcv, bcv, bcv, bcv);
        #pragma unroll
        for (int c2 = 0; c2 < CCH; ++c2) {
            const float wv = wcs[d][c2];
            acc.x = fmaf(wv, r[c2].x, acc.x);
            acc.y = fmaf(wv, r[c2].y, acc.y);
            acc.z = fmaf(wv, r[c2].z, acc.z);
            acc.w = fmaf(wv, r[c2].w, acc.w);
        }
        acc.x = fmaxf(acc.x, 0.f);
        acc.y = fmaxf(acc.y, 0.f);
        acc.z = fmaxf(acc.z, 0.f);
        acc.w = fmaxf(acc.w, 0.f);
        *reinterpret_cast<float4*>(&ybase[(size_t)d * NN * NN + m0]) = acc;
    }
}

extern "C" void kernel_launch(void* const* d_in, const int* in_sizes, int n_in,
                              void* d_out, int out_size, void* d_ws, size_t ws_size,
                              hipStream_t stream) {
    const float* x  = (const float*)d_in[0];
    const float* W1 = (const float*)d_in[1];
    const float* b1 = (const float*)d_in[2];
    const float* W2 = (const float*)d_in[3];
    const float* b2 = (const float*)d_in[4];
    const float* Wc = (const float*)d_in[5];
    const float* bc = (const float*)d_in[6];
    float* y  = (float*)d_out;
    float* ws = (float*)d_ws;   // B*C*N*N floats = 4 MiB intermediate "out"

    dim3 g1(BBATCH * CCH * (NN / GP));   // 4*16*32 = 2048 blocks
    k1_mlp<<<g1, 128, 0, stream>>>(x, W1, b1, W2, b2, ws);

    dim3 g2(BBATCH * NN);                // 512 blocks
    k2_conv<<<g2, 256, 0, stream>>>(ws, Wc, bc, y);
}

// Round 2
// 39.696 us; speedup vs baseline: 1.0026x; 1.0026x over previous
//
#include <hip/hip_runtime.h>

#define NN 128
#define CCH 16
#define BB 4
#define GP 2          // rows per block
#define HID 128
#define DOUT 128

// One block = (b, 2 consecutive rows p0,p0+1). 512 threads.
// Phase 1: thread (cq = t>>7, q = t&127) runs the 4->128->2 MLP for
//          c in {cq, cq+4, cq+8, cq+12}, p in {p0, p0+1}: h1 -> LDS s_out,
//          h0 -> block reduction -> diagonal.
// Phase 2: channel mix 16->128 + ReLU, streamed to y.
__global__ __launch_bounds__(512, 2) void fused_rey(
    const float* __restrict__ x, const float* __restrict__ W1,
    const float* __restrict__ b1, const float* __restrict__ W2,
    const float* __restrict__ b2, const float* __restrict__ Wc,
    const float* __restrict__ bc, float* __restrict__ y)
{
    __shared__ float4 w1s[HID];            // W1 rows
    __shared__ float4 wbs[HID];            // {b1[k], W2[0][k], W2[1][k], 0}
    __shared__ float  wcs[DOUT][CCH];      // 8 KB
    __shared__ float  bcs[DOUT];
    __shared__ float  s_out[CCH][GP][NN];  // 16 KB
    __shared__ float  s_part[8][4][GP];    // per-wave diag partials

    const int t   = threadIdx.x;
    const int bid = blockIdx.x;
    const int pg  = bid & 63;
    const int b   = bid >> 6;
    const int p0  = pg * GP;
    const int q   = t & 127;
    const int cq  = t >> 7;                // 0..3

    // ---- stage weights ----
    if (t < HID) {
        w1s[t] = reinterpret_cast<const float4*>(W1)[t];
        wbs[t] = make_float4(b1[t], W2[t], W2[HID + t], 0.f);
        bcs[t] = bc[t];
    }
    reinterpret_cast<float4*>(wcs)[t] = reinterpret_cast<const float4*>(Wc)[t];

    // ---- per-thread x loads (before barrier; latency overlaps staging) ----
    const float bb0 = b2[0], bb1 = b2[1];
    float x_pp[4][GP], x_pq[4][GP], x_qp[4][GP], x_qq[4];
    #pragma unroll
    for (int j = 0; j < 4; ++j) {
        const int c = cq + 4 * j;
        const float* xm = x + ((size_t)(b * CCH + c) << 14);
        x_qq[j] = xm[q * (NN + 1)];
        const float2 qp = *reinterpret_cast<const float2*>(&xm[q * NN + p0]);
        x_qp[j][0] = qp.x; x_qp[j][1] = qp.y;
        #pragma unroll
        for (int pp = 0; pp < GP; ++pp) {
            x_pp[j][pp] = xm[(p0 + pp) * (NN + 1)];
            x_pq[j][pp] = xm[(p0 + pp) * NN + q];
        }
    }
    float h0[4][GP], h1[4][GP];
    #pragma unroll
    for (int j = 0; j < 4; ++j)
        #pragma unroll
        for (int pp = 0; pp < GP; ++pp) { h0[j][pp] = bb0; h1[j][pp] = bb1; }

    __syncthreads();

    // ---- phase 1: hidden loop ----
    #pragma unroll 4
    for (int k = 0; k < HID; ++k) {
        const float4 w  = w1s[k];
        const float4 wb = wbs[k];
        #pragma unroll
        for (int j = 0; j < 4; ++j) {
            const float s = fmaf(w.w, x_qq[j], wb.x);   // shared across the 2 p's
            #pragma unroll
            for (int pp = 0; pp < GP; ++pp) {
                float hd = fmaf(w.x, x_pp[j][pp], s);
                hd = fmaf(w.y, x_pq[j][pp], hd);
                hd = fmaf(w.z, x_qp[j][pp], hd);
                hd = fmaxf(hd, 0.f);
                h0[j][pp] = fmaf(wb.y, hd, h0[j][pp]);
                h1[j][pp] = fmaf(wb.z, hd, h1[j][pp]);
            }
        }
    }

    // ---- write off-diagonal h1; exclude q==p from diag sum ----
    #pragma unroll
    for (int j = 0; j < 4; ++j) {
        const int c = cq + 4 * j;
        #pragma unroll
        for (int pp = 0; pp < GP; ++pp) {
            s_out[c][pp][q] = h1[j][pp];           // (p,p) slot overwritten below
            if (q == p0 + pp) h0[j][pp] = 0.f;
        }
    }

    // ---- diag reduction: wave shuffle then cross-wave combine ----
    const int wv = t >> 6;
    #pragma unroll
    for (int j = 0; j < 4; ++j)
        #pragma unroll
        for (int pp = 0; pp < GP; ++pp) {
            float v = h0[j][pp];
            for (int off = 32; off > 0; off >>= 1)
                v += __shfl_down(v, off, 64);
            if ((t & 63) == 0) s_part[wv][j][pp] = v;
        }
    __syncthreads();
    if (t < 32) {
        const int cq2 = t >> 3, j2 = (t >> 1) & 3, pp2 = t & 1;
        const int c2 = cq2 + 4 * j2;
        const float v = (s_part[cq2 * 2][j2][pp2] + s_part[cq2 * 2 + 1][j2][pp2])
                        * (1.0f / (NN - 1));
        s_out[c2][pp2][p0 + pp2] = v;
    }
    __syncthreads();

    // ---- phase 2: y[b,d,p,:] = relu(sum_c out[c]*Wc[d][c] + bc[d]) ----
    const int m0   = (t & 31) * 4;
    const int dgrp = t >> 5;               // 0..15, 8 d's each
    #pragma unroll
    for (int pp = 0; pp < GP; ++pp) {
        float4 r[CCH];
        #pragma unroll
        for (int c = 0; c < CCH; ++c)
            r[c] = *reinterpret_cast<const float4*>(&s_out[c][pp][m0]);
        #pragma unroll
        for (int dd = 0; dd < 8; ++dd) {
            const int d = dgrp * 8 + dd;
            const float4 wr0 = reinterpret_cast<const float4*>(&wcs[d][0])[0];
            const float4 wr1 = reinterpret_cast<const float4*>(&wcs[d][0])[1];
            const float4 wr2 = reinterpret_cast<const float4*>(&wcs[d][0])[2];
            const float4 wr3 = reinterpret_cast<const float4*>(&wcs[d][0])[3];
            const float wv16[16] = { wr0.x, wr0.y, wr0.z, wr0.w,
                                     wr1.x, wr1.y, wr1.z, wr1.w,
                                     wr2.x, wr2.y, wr2.z, wr2.w,
                                     wr3.x, wr3.y, wr3.z, wr3.w };
            const float bcv = bcs[d];
            float4 acc = make_float4(bcv, bcv, bcv, bcv);
            #pragma unroll
            for (int c = 0; c < CCH; ++c) {
                acc.x = fmaf(wv16[c], r[c].x, acc.x);
                acc.y = fmaf(wv16[c], r[c].y, acc.y);
                acc.z = fmaf(wv16[c], r[c].z, acc.z);
                acc.w = fmaf(wv16[c], r[c].w, acc.w);
            }
            acc.x = fmaxf(acc.x, 0.f);
            acc.y = fmaxf(acc.y, 0.f);
            acc.z = fmaxf(acc.z, 0.f);
            acc.w = fmaxf(acc.w, 0.f);
            float* yp = y + ((((size_t)(b * DOUT + d)) * NN + (p0 + pp)) * NN + m0);
            *reinterpret_cast<float4*>(yp) = acc;
        }
    }
}

extern "C" void kernel_launch(void* const* d_in, const int* in_sizes, int n_in,
                              void* d_out, int out_size, void* d_ws, size_t ws_size,
                              hipStream_t stream) {
    const float* x  = (const float*)d_in[0];
    const float* W1 = (const float*)d_in[1];
    const float* b1 = (const float*)d_in[2];
    const float* W2 = (const float*)d_in[3];
    const float* b2 = (const float*)d_in[4];
    const float* Wc = (const float*)d_in[5];
    const float* bc = (const float*)d_in[6];
    float* y = (float*)d_out;

    dim3 grid(BB * (NN / GP));   // 4*64 = 256 blocks = 1 per CU
    fused_rey<<<grid, 512, 0, stream>>>(x, W1, b1, W2, b2, Wc, bc, y);
}